// Round 12
// baseline (251.769 us; speedup 1.0000x reference)
//
#include <hip/hip_runtime.h>
#include <cstdint>
#include <cstddef>

// LSTM cell: B=16384, IN=HID=512.
// R14 resubmit #3 (three consecutive GPU-acquisition timeouts; never ran).
// R14 = R13 structure with INLINE-ASM ds_read_b128 fragment loads + manual
// counted lgkmcnt(4). Diagnosis: R7-R13 (six schedules) all ~30% MfmaUtil,
// ~1000cy/phase stall invariant to schedule => the binding wait is
// COMPILER-INSERTED: plain-C lds[] reads alias global_load_lds writes, so
// hipcc's waitcnt pass emits conservative vmcnt waits before every fragment
// cluster -> every phase eats the just-issued stage's L2 latency, lockstep.
// Fix: asm ds_reads (opaque to the waitcnt pass; no auto-vmcnt/lgkm) with
// manual uniform lgkmcnt(4) (operands issued one phase earlier; exactly the
// 4 newest DS ops are this phase's issues) + sched_barrier(0) (rule #18).
// Register-hazard audit: every frag set is drained (by a lgkmcnt(4)) before
// its rewrite; epilogue waits lgkmcnt(0) for the dangling tail reads.
// vmcnt(6)-per-tile staging ledger and T2 swizzle unchanged (R10: 0 confl).

#define BATCH 16384
#define KDIM  1024
#define NPK   2048
#define HIDN  512

#define BM 256
#define BN 256
#define BK 64
#define NT (KDIM / BK)   // 16

typedef __bf16 bf16x8 __attribute__((ext_vector_type(8)));
typedef float  f32x4  __attribute__((ext_vector_type(4)));

__device__ __forceinline__ unsigned short f2bf(float f) {
  unsigned int u = __builtin_bit_cast(unsigned int, f);
  u += 0x7fffu + ((u >> 16) & 1u);   // RNE
  return (unsigned short)(u >> 16);
}

__device__ __forceinline__ float fast_sigmoid(float x) {
  return __builtin_amdgcn_rcpf(1.0f + __expf(-x));
}
__device__ __forceinline__ float fast_tanh(float x) {
  return 1.0f - 2.0f * __builtin_amdgcn_rcpf(1.0f + __expf(2.0f * x));
}

// async global->LDS, 16 B per lane; LDS dest = wave-uniform base + lane*16
__device__ __forceinline__ void gload_lds16(const void* gp, void* lds_wave_base) {
  auto g = (const __attribute__((address_space(1))) unsigned int*)(unsigned long long)gp;
  auto l = (__attribute__((address_space(3))) unsigned int*)
           (unsigned int)(unsigned long long)lds_wave_base;
  __builtin_amdgcn_global_load_lds(g, l, 16, 0, 0);
}

// ---------------- prep kernels (unchanged) ----------------
__global__ __launch_bounds__(256) void pack_a(const float* __restrict__ x,
                                              const float* __restrict__ h,
                                              unsigned short* __restrict__ A) {
  int c = blockIdx.x * 256 + threadIdx.x;   // chunk of 8 elements
  int idx = c << 3;
  int b = idx >> 10;          // row
  int k = idx & 1023;         // col
  const float* src = (k < 512) ? (x + (size_t)b * 512 + k)
                               : (h + (size_t)b * 512 + (k - 512));
  float4 lo = ((const float4*)src)[0];
  float4 hi = ((const float4*)src)[1];
  union { unsigned short s[8]; uint4 u; } o;
  o.s[0]=f2bf(lo.x); o.s[1]=f2bf(lo.y); o.s[2]=f2bf(lo.z); o.s[3]=f2bf(lo.w);
  o.s[4]=f2bf(hi.x); o.s[5]=f2bf(hi.y); o.s[6]=f2bf(hi.z); o.s[7]=f2bf(hi.w);
  ((uint4*)A)[c] = o.u;
}

struct GatePtrs {
  const float* wx[4];  // gate order: i, g, f, o
  const float* wh[4];
  const float* bx[4];
  const float* bh[4];
};

// W row-major bf16 [2048][1024], rows packed r = b*128 + wn*64 + gate*16 + jl,
// j = b*32 + wn*16 + jl.
__global__ __launch_bounds__(256) void pack_w(GatePtrs P,
                                              unsigned short* __restrict__ W,
                                              float* __restrict__ bias) {
  int c = blockIdx.x * 256 + threadIdx.x;   // chunk of 8, 128 chunks per row
  int r = c >> 7;
  int k = (c & 127) << 3;
  int b    = r >> 7;
  int rem  = r & 127;
  int wn   = (rem >> 6) & 1;
  int gate = (rem >> 4) & 3;
  int jl   = rem & 15;
  int j = b * 32 + wn * 16 + jl;
  const float* src = (k < 512) ? (P.wx[gate] + (size_t)j * 512 + k)
                               : (P.wh[gate] + (size_t)j * 512 + (k - 512));
  float4 lo = ((const float4*)src)[0];
  float4 hi = ((const float4*)src)[1];
  union { unsigned short s[8]; uint4 u; } o;
  o.s[0]=f2bf(lo.x); o.s[1]=f2bf(lo.y); o.s[2]=f2bf(lo.z); o.s[3]=f2bf(lo.w);
  o.s[4]=f2bf(hi.x); o.s[5]=f2bf(hi.y); o.s[6]=f2bf(hi.z); o.s[7]=f2bf(hi.w);
  ((uint4*)W)[c] = o.u;
  if ((c & 127) == 0) bias[r] = P.bx[gate][j] + P.bh[gate][j];
}

// ---------------- fused GEMM + LSTM epilogue ----------------

__global__ __launch_bounds__(512, 2) void lstm_gemm(
    const unsigned short* __restrict__ A,    // [16384,1024] bf16 row-major
    const unsigned short* __restrict__ W,    // [2048,1024] bf16 packed rows
    const float* __restrict__ bias,          // [2048] packed
    const float* __restrict__ Cin,           // [16384,512]
    float* __restrict__ Hout,                // [16384,512]
    float* __restrict__ Cout) {              // [16384,512]
  // 2 buffers x { Akc0, Akc1, Bkc0, Bkc1 } regions, each [256 rows][32 cols]
  // bf16 = 8192 ushorts = 16 KB. Total 128 KB -> 1 block/CU.
  __shared__ __align__(16) unsigned short lds[2 * 32768];

  const int tid  = threadIdx.x;
  const int lane = tid & 63;
  const int wv   = tid >> 6;     // 0..7
  const int wm   = wv >> 2;      // 0..1 (wave row; 2 x 128 = 256)
  const int wn   = wv & 3;       // 0..3 (wave col; 4 x 64  = 256)

  // XCD-aware swizzle: 512 blocks, nwg%8==0 -> simple swizzle bijective.
  const int lin = blockIdx.x;    // 0..511
  const int xcd = lin & 7;
  const int idx = lin >> 3;
  const int bn  = idx & 7;       // 0..7
  const int bm  = (idx >> 3) * 8 + xcd;  // 0..63

  // ---- staging addressing: one region = 2 gload_lds16 per thread ----
  // T2 write side: LDS dest linear; global source column pre-swizzled:
  // lane (srow, sl) fetches k-chunk sl ^ ((srow>>1)&3). Rows srow, srow+16
  // share the swizzle constant.
  const int srow = lane >> 2;            // 0..15
  const int scol = (((lane & 3) ^ ((srow >> 1) & 3)) << 3);  // ushort offset
  const unsigned short* gA = A + (size_t)(bm * 256 + wv * 32 + srow) * KDIM + scol;
  const unsigned short* gB = W + (size_t)(bn * 256 + wv * 32 + srow) * KDIM + scol;
  const int lA = wv * 1024;              // wave's 32-row slab (ushorts) in a region

#define REG_A(b, c) ((b) * 32768 + (c) * 8192)
#define REG_B(b, c) ((b) * 32768 + 16384 + (c) * 8192)

#define STAGE_A(b, c, tt) do {                                      \
    const unsigned short* s_ = gA + (tt) * 64 + (c) * 32;           \
    gload_lds16(s_,            &lds[REG_A(b, c) + lA]);             \
    gload_lds16(s_ + 16 * KDIM, &lds[REG_A(b, c) + lA + 512]);      \
  } while (0)
#define STAGE_B(b, c, tt) do {                                      \
    const unsigned short* s_ = gB + (tt) * 64 + (c) * 32;           \
    gload_lds16(s_,            &lds[REG_B(b, c) + lA]);             \
    gload_lds16(s_ + 16 * KDIM, &lds[REG_B(b, c) + lA + 512]);      \
  } while (0)

  // ---- fragment addressing ----
  // T2 read side: lane (lrow, s=lane>>4) reads slot s ^ ((lrow>>1)&3);
  // involution cancels -> correct k-chunk, conflict-free (R10: 0 conflicts).
  const int lrow = lane & 15;
  const int kg   = (((lane >> 4) ^ ((lrow >> 1) & 3)) << 3);  // ushort offset
  const int aoff = wm * 4096 + lrow * 32 + kg;   // + h*2048 + mi*512
  const int boff = wn * 2048 + lrow * 32 + kg;   // + ni*512

  f32x4 acc[8][4] = {};   // [m: h*4+mi][gate ni]
  bf16x8 afA[4], afB[4];  // ping-pong A-fragment sets (static names)
  bf16x8 bfr[4];          // single B-fragment set, reloaded post-last-use

// asm ds_read: opaque to the waitcnt pass -> no compiler-inserted vmcnt/lgkm.
// Addr truncation to 32-bit LDS offset = same trick gload_lds16 uses (HW-OK).
#define DS_READ128(dst, idx_)                                                  \
  asm volatile("ds_read_b128 %0, %1"                                           \
               : "=v"(dst)                                                     \
               : "v"((unsigned int)(unsigned long long)&lds[idx_]))

#define LOAD_AF_TO(dst, b, c, h) do {                                          \
    DS_READ128(dst[0], REG_A(b, c) + aoff + (h) * 2048 + 0 * 512);             \
    DS_READ128(dst[1], REG_A(b, c) + aoff + (h) * 2048 + 1 * 512);             \
    DS_READ128(dst[2], REG_A(b, c) + aoff + (h) * 2048 + 2 * 512);             \
    DS_READ128(dst[3], REG_A(b, c) + aoff + (h) * 2048 + 3 * 512);             \
  } while (0)
#define LOAD_BF_TO(dst, b, c) do {                                             \
    DS_READ128(dst[0], REG_B(b, c) + boff + 0 * 512);                          \
    DS_READ128(dst[1], REG_B(b, c) + boff + 1 * 512);                          \
    DS_READ128(dst[2], REG_B(b, c) + boff + 2 * 512);                          \
    DS_READ128(dst[3], REG_B(b, c) + boff + 3 * 512);                          \
  } while (0)

#define MFMA_BLK(h, aset) do {                                                 \
    __builtin_amdgcn_s_setprio(1);                                             \
    _Pragma("unroll")                                                          \
    for (int mi = 0; mi < 4; ++mi)                                             \
      _Pragma("unroll")                                                        \
      for (int ni = 0; ni < 4; ++ni)                                           \
        acc[(h) * 4 + mi][ni] = __builtin_amdgcn_mfma_f32_16x16x32_bf16(       \
            aset[mi], bfr[ni], acc[(h) * 4 + mi][ni], 0, 0, 0);                \
    __builtin_amdgcn_s_setprio(0);                                             \
  } while (0)

#define BAR()  __builtin_amdgcn_s_barrier()
#define SCB()  __builtin_amdgcn_sched_barrier(0)
// counted wait: operands were issued one phase earlier; exactly 4 newer DS
// ops (this phase's frag issues) outstanding. SCB pins MFMA below (rule #18).
#define WAITL4() do { asm volatile("s_waitcnt lgkmcnt(4)" ::: "memory"); SCB(); } while (0)

  // ---- prologue ----
  // [Bkc0(0), Akc0(0), Bkc1(0), Akc1(0), Bkc0(1), Akc0(1), Bkc1(1)] = 14 loads
  // vmcnt(6) -> 3 newest regions (t=1 partial) in flight; all t=0 certified.
  STAGE_B(0, 0, 0); STAGE_A(0, 0, 0); STAGE_B(0, 1, 0); STAGE_A(0, 1, 0);
  STAGE_B(1, 0, 1); STAGE_A(1, 0, 1); STAGE_B(1, 1, 1);
  asm volatile("s_waitcnt vmcnt(6)" ::: "memory");
  BAR(); SCB();
  LOAD_AF_TO(afA, 0, 0, 0);   // frags for t=0 p0; drain under loop entry
  LOAD_BF_TO(bfr, 0, 0);

#pragma unroll 2
  for (int t = 0; t < NT; ++t) {
    const int cur = t & 1;
    const int nxt = cur ^ 1;
    const int t1 = (t + 1 < NT) ? t + 1 : NT - 1;  // clamp: redundant re-stage,
    const int t2 = (t + 2 < NT) ? t + 2 : NT - 1;  // keeps vmcnt counts uniform
    // ---- p0: MFMA(kc0,h0)[afA,bfr]; issue afB <- (kc0,h1) ----
    // lgkm ledger: outstanding {afA,bfr}(8) + afB(4) -> wait 4 drains afA,bfr.
    LOAD_AF_TO(afB, cur, 0, 1);
    STAGE_A(nxt, 1, t1);           // buf[nxt].Akc1: readers drained by t-1 waits
    WAITL4();
    MFMA_BLK(0, afA);
    SCB();
    BAR();
    // ---- p1: MFMA(kc0,h1)[afB,bfr]; issue afA <- (kc1,h0); reload bfr <- kc1 ----
    // ledger: {afB}+afA(4) -> wait 4 leaves afA; afB,bfr drained.
    LOAD_AF_TO(afA, cur, 1, 0);
    STAGE_B(cur, 0, t2);           // overwrites Bkc0(cur): reads drained at p0 wait
    WAITL4();
    MFMA_BLK(1, afB);
    SCB();                         // bfr reload stays below its last use
    LOAD_BF_TO(bfr, cur, 1);
    BAR();
    // ---- p2: MFMA(kc1,h0)[afA,bfr]; issue afB <- (kc1,h1) ----
    // ledger: {afA,bfr}+afB(4) -> wait 4 leaves afB; afA,bfr(kc1) drained.
    LOAD_AF_TO(afB, cur, 1, 1);
    STAGE_A(cur, 0, t2);           // overwrites Akc0(cur): drained at p0/p1 waits
    WAITL4();
    MFMA_BLK(0, afA);
    SCB();
    BAR();
    // ---- p3: stage; vmcnt(6); issue t+1 frags; MFMA(kc1,h1)[afB,bfr] ----
    STAGE_B(cur, 1, t2);           // overwrites Bkc1(cur): drained at p2 wait
    // 14 stage-loads outstanding; keep newest 6 = {p1,p2,p3 stages}(t+2 data);
    // certifies p0's A(t+1,kc1) and all older -> tile t+1 fully resident.
    asm volatile("s_waitcnt vmcnt(6)" ::: "memory");
    LOAD_AF_TO(afA, nxt, 0, 0);    // unconditional (uniform lgkm counts; tail
    WAITL4();                      //  reads stale buf -> values unused, safe)
    MFMA_BLK(1, afB);
    SCB();
    LOAD_BF_TO(bfr, nxt, 0);       // after bfr's last use (kc1)
    BAR();
  }
  // drain tail stages AND dangling frag reads (register-reuse hazard in epilogue)
  asm volatile("s_waitcnt vmcnt(0) lgkmcnt(0)" ::: "memory");
  SCB();

  // ---- epilogue: ni == gate (0=i,1=g,2=f,3=o); lane's j fixed ----
  // W-packed row = bn*256 + wn*64 + ni*16 + jl decodes (pack_w layout) to
  // j = (bn*2 + (wn>>1))*32 + (wn&1)*16 + jl, gate = ni.
  const int jl = lane & 15;
  const int rq = (lane >> 4) << 2;
  const int j  = (bn * 2 + (wn >> 1)) * 32 + (wn & 1) * 16 + jl;
  float bv[4];
#pragma unroll
  for (int ni = 0; ni < 4; ++ni)
    bv[ni] = bias[bn * 256 + wn * 64 + ni * 16 + jl];

#pragma unroll
  for (int mi = 0; mi < 8; ++mi) {
    const int row0 = bm * 256 + wm * 128 + (mi >> 2) * 64 + (mi & 3) * 16 + rq;
#pragma unroll
    for (int r = 0; r < 4; ++r) {
      int row = row0 + r;
      float iv = fast_sigmoid(acc[mi][0][r] + bv[0]);
      float gv = fast_tanh   (acc[mi][1][r] + bv[1]);
      float fv = fast_sigmoid(acc[mi][2][r] + bv[2]);
      float ov = fast_sigmoid(acc[mi][3][r] + bv[3]);
      float cold = Cin[(size_t)row * HIDN + j];
      float cnew = fv * cold + iv * gv;
      Hout[(size_t)row * HIDN + j] = ov * fast_tanh(cnew);
      Cout[(size_t)row * HIDN + j] = cnew;
    }
  }
}

// ---------------- launch ----------------

extern "C" void kernel_launch(void* const* d_in, const int* in_sizes, int n_in,
                              void* d_out, int out_size, void* d_ws, size_t ws_size,
                              hipStream_t stream) {
  const float* x   = (const float*)d_in[0];
  const float* h   = (const float*)d_in[1];
  const float* c   = (const float*)d_in[2];
  const float* Wxi = (const float*)d_in[3];  const float* bxi = (const float*)d_in[4];
  const float* Wxo = (const float*)d_in[5];  const float* bxo = (const float*)d_in[6];
  const float* Wxf = (const float*)d_in[7];  const float* bxf = (const float*)d_in[8];
  const float* Wxg = (const float*)d_in[9];  const float* bxg = (const float*)d_in[10];
  const float* Whi = (const float*)d_in[11]; const float* bhi = (const float*)d_in[12];
  const float* Who = (const float*)d_in[13]; const float* bho = (const float*)d_in[14];
  const float* Whf = (const float*)d_in[15]; const float* bhf = (const float*)d_in[16];
  const float* Whg = (const float*)d_in[17]; const float* bhg = (const float*)d_in[18];

  char* ws = (char*)d_ws;
  unsigned short* Apack = (unsigned short*)ws;                              // 32 MB
  unsigned short* Wpack = (unsigned short*)(ws + (size_t)BATCH * KDIM * 2); // 4 MB
  float* biasp = (float*)(ws + (size_t)BATCH * KDIM * 2 + (size_t)NPK * KDIM * 2);

  pack_a<<<(BATCH * KDIM / 8) / 256, 256, 0, stream>>>(x, h, Apack);

  GatePtrs P;
  P.wx[0] = Wxi; P.wx[1] = Wxg; P.wx[2] = Wxf; P.wx[3] = Wxo;
  P.wh[0] = Whi; P.wh[1] = Whg; P.wh[2] = Whf; P.wh[3] = Who;
  P.bx[0] = bxi; P.bx[1] = bxg; P.bx[2] = bxf; P.bx[3] = bxo;
  P.bh[0] = bhi; P.bh[1] = bhg; P.bh[2] = bhf; P.bh[3] = bho;
  pack_w<<<(NPK * KDIM / 8) / 256, 256, 0, stream>>>(P, Wpack, biasp);

  float* Hout = (float*)d_out;
  float* Cout = Hout + (size_t)BATCH * HIDN;
  lstm_gemm<<<dim3((BATCH / BM) * (NPK / BN)), 512, 0, stream>>>(
      Apack, Wpack, biasp, c, Hout, Cout);
}